// Round 3
// baseline (265.949 us; speedup 1.0000x reference)
//
#include <hip/hip_runtime.h>

// ---------------------------------------------------------------------------
// RMSNormSparse: out = weight * (mask?x:0) * rsqrt(mean((mask?x:0)^2) + eps)
// B=4, S=4096, D=4096, fp32 in/out. Memory-bound streaming kernel.
//
// Round-3 structure: persistent BLOCK-PER-ROW (256 thr, 16 floats/thread)
// with explicit next-row prefetch held in registers across a MANUAL barrier
// (s_waitcnt lgkmcnt(0) + s_barrier -- hipcc's __syncthreads() drains
// vmcnt(0), which would kill the prefetch). __launch_bounds__(256,4) gives
// a 128-VGPR budget so v[4] (masked x), xn[4] (prefetch), wv[4] (weight,
// loop-invariant, loaded once per block) stay register-resident -- round 2
// proved the compiler otherwise rematerializes global loads (FETCH doubled).
//
// Mask layout flag (d_ws): 0 = uint8 (confirmed by round-1/2 FETCH_SIZE and
// passing validation), 1 = int32, 2 = float32. Fast kernel runs iff flag==0;
// a grid-stride generic kernel runs iff flag!=0. Both launched every call.
// ---------------------------------------------------------------------------

#define EPS_RMS 1e-5f

typedef float f32x4 __attribute__((ext_vector_type(4)));

__global__ void detect_mask_kernel(const unsigned char* __restrict__ mb,
                                   int* __restrict__ flag) {
    __shared__ int nz_off;  // any nonzero byte at offset%4 != 0
    __shared__ int f3;      // any 0x3f byte at offset%4 == 3  -> float32
    if (threadIdx.x == 0) { nz_off = 0; f3 = 0; }
    __syncthreads();
    unsigned int i = threadIdx.x * 4u;  // 256 threads x 4 bytes = 1024 bytes
    unsigned char b1 = mb[i + 1], b2 = mb[i + 2], b3 = mb[i + 3];
    if ((b1 | b2 | b3) != 0) atomicOr(&nz_off, 1);
    if (b3 == 0x3fu) atomicOr(&f3, 1);
    __syncthreads();
    if (threadIdx.x == 0) {
        *flag = f3 ? 2 : (nz_off ? 0 : 1);
    }
}

// Fast path: D == 4096, uint8 mask. Persistent block-per-row + prefetch.
__global__ __launch_bounds__(256, 4) void rmsnorm_sparse_fast4096(
    const float* __restrict__ x,
    const unsigned char* __restrict__ mask,
    const float* __restrict__ weight,
    float* __restrict__ out,
    const int* __restrict__ flag_p,
    int nrows, int rstride) {
    if (*flag_p != 0) return;  // uniform: mask is not uint8 -> generic runs

    const int t = threadIdx.x;
    __shared__ float ws[2][4];

    // Loop-invariant weight: 16 KB row, L2-hot, loaded once per block.
    const f32x4* __restrict__ w4 = (const f32x4*)weight;
    f32x4 wv[4];
#pragma unroll
    for (int i = 0; i < 4; ++i) wv[i] = w4[t + 256 * i];

    const f32x4* __restrict__ x4 = (const f32x4*)x;
    const uchar4* __restrict__ m4 = (const uchar4*)mask;
    f32x4* __restrict__ o4 = (f32x4*)out;

    int r = blockIdx.x;
    if (r >= nrows) return;  // uniform per block

    // Preload first row.
    f32x4 xv[4];
    uchar4 mm[4];
    {
        const size_t b = (size_t)r * 1024u;
#pragma unroll
        for (int i = 0; i < 4; ++i) xv[i] = x4[b + t + 256 * i];
#pragma unroll
        for (int i = 0; i < 4; ++i) mm[i] = m4[b + t + 256 * i];
    }

    int parity = 0;
    for (;;) {
        const int rn = r + rstride;
        const bool has_next = rn < nrows;

        // Prefetch next row BEFORE the reduce; these vmem loads stay in
        // flight across the manual barrier below.
        f32x4 xn[4];
        uchar4 mn[4];
        if (has_next) {
            const size_t nb = (size_t)rn * 1024u;
#pragma unroll
            for (int i = 0; i < 4; ++i) xn[i] = x4[nb + t + 256 * i];
#pragma unroll
            for (int i = 0; i < 4; ++i) mn[i] = m4[nb + t + 256 * i];
        }

        // Masked values + sum of squares (v[] stays live through the store).
        float s = 0.f;
        f32x4 v[4];
#pragma unroll
        for (int i = 0; i < 4; ++i) {
            f32x4 a = xv[i];
            const uchar4 u = mm[i];
            a.x = u.x ? a.x : 0.f;
            a.y = u.y ? a.y : 0.f;
            a.z = u.z ? a.z : 0.f;
            a.w = u.w ? a.w : 0.f;
            v[i] = a;
            s += a.x * a.x + a.y * a.y + a.z * a.z + a.w * a.w;
        }
#pragma unroll
        for (int off = 1; off < 64; off <<= 1) s += __shfl_xor(s, off);

        if ((t & 63) == 0) ws[parity][t >> 6] = s;
        // Manual barrier: wait LDS write only -- do NOT drain vmcnt (the
        // prefetch). __syncthreads() would emit s_waitcnt vmcnt(0).
        asm volatile("s_waitcnt lgkmcnt(0)" ::: "memory");
        __builtin_amdgcn_s_barrier();
        asm volatile("" ::: "memory");

        const float total =
            ws[parity][0] + ws[parity][1] + ws[parity][2] + ws[parity][3];
        const float scale = rsqrtf(total * (1.0f / 4096.0f) + EPS_RMS);

        const size_t ob = (size_t)r * 1024u;
#pragma unroll
        for (int i = 0; i < 4; ++i) o4[ob + t + 256 * i] = v[i] * scale * wv[i];

        if (!has_next) break;
        r = rn;
#pragma unroll
        for (int i = 0; i < 4; ++i) { xv[i] = xn[i]; mm[i] = mn[i]; }
        parity ^= 1;
    }
}

// Generic grid-stride fallback (any D; int32/float32 mask; correctness only).
// require_nonzero_flag: if 1, early-exit when flag==0 (fast kernel handled it).
__global__ void rmsnorm_sparse_generic(const float* __restrict__ x,
                                       const void* __restrict__ mask,
                                       const float* __restrict__ weight,
                                       float* __restrict__ out,
                                       const int* __restrict__ flag_p, int D,
                                       int nrows, int require_nonzero_flag) {
    const int flag = *flag_p;
    if (require_nonzero_flag && flag == 0) return;

    const int t = threadIdx.x;
    const int lane = t & 63;
    const int wave = t >> 6;
    const int nw = (blockDim.x + 63) / 64;
    __shared__ float ws[16];

    for (int row = blockIdx.x; row < nrows; row += gridDim.x) {
        const size_t base = (size_t)row * (size_t)D;

        float s = 0.f;
        for (int d = t; d < D; d += blockDim.x) {
            float xv = x[base + d];
            bool m;
            if (flag == 0)
                m = ((const unsigned char*)mask)[base + d] != 0;
            else if (flag == 1)
                m = ((const int*)mask)[base + d] != 0;
            else
                m = ((const float*)mask)[base + d] != 0.f;
            float xm = m ? xv : 0.f;
            s += xm * xm;
        }
#pragma unroll
        for (int off = 32; off > 0; off >>= 1) s += __shfl_down(s, off);
        if (lane == 0) ws[wave] = s;
        __syncthreads();
        float total = 0.f;
        for (int i = 0; i < nw; ++i) total += ws[i];
        const float scale = rsqrtf(total / (float)D + EPS_RMS);
        __syncthreads();  // protect ws before next iteration's writes

        for (int d = t; d < D; d += blockDim.x) {
            float xv = x[base + d];
            bool m;
            if (flag == 0)
                m = ((const unsigned char*)mask)[base + d] != 0;
            else if (flag == 1)
                m = ((const int*)mask)[base + d] != 0;
            else
                m = ((const float*)mask)[base + d] != 0.f;
            float xm = m ? xv : 0.f;
            out[base + d] = weight[d] * xm * scale;
        }
    }
}

extern "C" void kernel_launch(void* const* d_in, const int* in_sizes, int n_in,
                              void* d_out, int out_size, void* d_ws,
                              size_t ws_size, hipStream_t stream) {
    const float* x = (const float*)d_in[0];
    const void* mask = d_in[1];
    const float* weight = (const float*)d_in[2];
    float* out = (float*)d_out;

    const int D = in_sizes[2];         // weight length
    const int rows = in_sizes[0] / D;  // B*S

    int* flag = (int*)d_ws;
    detect_mask_kernel<<<1, 256, 0, stream>>>((const unsigned char*)mask, flag);

    if (D == 4096) {
        const int blocks = rows < 2048 ? rows : 2048;
        rmsnorm_sparse_fast4096<<<blocks, 256, 0, stream>>>(
            x, (const unsigned char*)mask, weight, out, flag, rows, blocks);
        // Rare-layout fallback (flag != 0): grid-stride, early-exits if uint8.
        rmsnorm_sparse_generic<<<blocks, 256, 0, stream>>>(
            x, mask, weight, out, flag, D, rows, /*require_nonzero_flag=*/1);
    } else {
        const int blocks = rows < 2048 ? rows : 2048;
        rmsnorm_sparse_generic<<<blocks, 256, 0, stream>>>(
            x, mask, weight, out, flag, D, rows, /*require_nonzero_flag=*/0);
    }
}

// Round 5
// 147.132 us; speedup vs baseline: 1.8076x; 1.8076x over previous
//
#include <hip/hip_runtime.h>

// ---------------------------------------------------------------------------
// RMSNormSparse: out = weight * (mask?x:0) * rsqrt(mean((mask?x:0)^2) + eps)
// B=4, S=4096, D=4096. ALL TENSORS FP32; mask is fp32 0.0/1.0.
//
// Mask-layout evidence (rounds 0-4): fp32 1.0f has byte3==0x3f -> the round-1
// detector computed flag=2 (float32) every round; rounds 1-3 passed through
// fp32-mask branches; round 4's hard-coded uint8 FAILED (absmax 15). FETCH
// arithmetic closes only with a 256 MiB fp32 mask: x+mask = 512 MiB vs
// 256 MiB L3 -> ~50% hits -> one-pass kernels fetch ~262 MiB (round 1),
// two-pass paths ~524 MiB (rounds 2-3). Mask test is BITWISE word != 0
// (correct for fp32 0/1 and int 0/1 alike).
//
// Structure: persistent BLOCK-PER-ROW (256 thr, 16 floats/thread) with
// next-row prefetch (x + mask) held in registers across a MANUAL barrier:
//   s_waitcnt lgkmcnt(0) + s_barrier   (NOT __syncthreads, which drains
//   vmcnt(0) and would kill the prefetch -- the round-1 2.95 TB/s limiter).
// Parity-double-buffered ws[2][4] makes one barrier per row sufficient.
// __launch_bounds__(256,4) = 128-VGPR budget; live data ~80 VGPRs (wv 16,
// xv 16, mm 16, xn 16, mn 16) so nothing rematerializes (round-2 lesson:
// FETCH doubles if the compiler re-issues global loads). NT stores keep L3
// for the 512 MiB of re-read inputs.
// ---------------------------------------------------------------------------

#define EPS_RMS 1e-5f

typedef float f32x4 __attribute__((ext_vector_type(4)));
typedef int i32x4 __attribute__((ext_vector_type(4)));

__global__ __launch_bounds__(256, 4) void rmsnorm_sparse_fast4096(
    const float* __restrict__ x,
    const int* __restrict__ mask,  // fp32 0.0/1.0 viewed as words; !=0 = keep
    const float* __restrict__ weight,
    float* __restrict__ out,
    int nrows, int rstride) {
    const int t = threadIdx.x;
    __shared__ float ws[2][4];

    // Loop-invariant weight row: loaded once per block, lives in registers.
    const f32x4* __restrict__ w4 = (const f32x4*)weight;
    f32x4 wv[4];
#pragma unroll
    for (int i = 0; i < 4; ++i) wv[i] = w4[t + 256 * i];

    const f32x4* __restrict__ x4 = (const f32x4*)x;
    const i32x4* __restrict__ m4 = (const i32x4*)mask;
    f32x4* __restrict__ o4 = (f32x4*)out;

    int r = blockIdx.x;
    if (r >= nrows) return;  // uniform per block (never true with our grid)

    // Preload first row (x + mask words).
    f32x4 xv[4];
    i32x4 mm[4];
    {
        const size_t b = (size_t)r * 1024u;
#pragma unroll
        for (int i = 0; i < 4; ++i) xv[i] = x4[b + t + 256 * i];
#pragma unroll
        for (int i = 0; i < 4; ++i) mm[i] = m4[b + t + 256 * i];
    }

    int parity = 0;
    for (;;) {
        const int rn = r + rstride;
        const bool has_next = rn < nrows;  // uniform per block

        // Prefetch next row BEFORE the reduce; these vmem loads stay in
        // flight across the manual barrier below.
        f32x4 xn[4];
        i32x4 mn[4];
        if (has_next) {
            const size_t nb = (size_t)rn * 1024u;
#pragma unroll
            for (int i = 0; i < 4; ++i) xn[i] = x4[nb + t + 256 * i];
#pragma unroll
            for (int i = 0; i < 4; ++i) mn[i] = m4[nb + t + 256 * i];
        }

        // Masked values + sum of squares (v[] stays live through the store).
        float s = 0.f;
        f32x4 v[4];
#pragma unroll
        for (int i = 0; i < 4; ++i) {
            f32x4 a = xv[i];
            const i32x4 u = mm[i];
            a.x = (u.x != 0) ? a.x : 0.f;
            a.y = (u.y != 0) ? a.y : 0.f;
            a.z = (u.z != 0) ? a.z : 0.f;
            a.w = (u.w != 0) ? a.w : 0.f;
            v[i] = a;
            s += a.x * a.x + a.y * a.y + a.z * a.z + a.w * a.w;
        }
#pragma unroll
        for (int off = 1; off < 64; off <<= 1) s += __shfl_xor(s, off);

        if ((t & 63) == 0) ws[parity][t >> 6] = s;
        // Manual barrier: wait LDS traffic only -- do NOT drain vmcnt (the
        // prefetch). __syncthreads() would emit s_waitcnt vmcnt(0).
        asm volatile("s_waitcnt lgkmcnt(0)" ::: "memory");
        __builtin_amdgcn_s_barrier();
        asm volatile("" ::: "memory");

        const float total =
            ws[parity][0] + ws[parity][1] + ws[parity][2] + ws[parity][3];
        const float scale = rsqrtf(total * (1.0f / 4096.0f) + EPS_RMS);

        const size_t ob = (size_t)r * 1024u;
#pragma unroll
        for (int i = 0; i < 4; ++i) {
            const f32x4 o = v[i] * scale * wv[i];
            __builtin_nontemporal_store(o, &o4[ob + t + 256 * i]);
        }

        if (!has_next) break;
        r = rn;
#pragma unroll
        for (int i = 0; i < 4; ++i) { xv[i] = xn[i]; mm[i] = mn[i]; }
        parity ^= 1;
    }
}

// Generic fallback for D != 4096 (fp32/int word mask; correctness only).
__global__ void rmsnorm_sparse_generic(const float* __restrict__ x,
                                       const int* __restrict__ mask,
                                       const float* __restrict__ weight,
                                       float* __restrict__ out, int D,
                                       int nrows) {
    const int t = threadIdx.x;
    const int lane = t & 63;
    const int wave = t >> 6;
    const int nw = (blockDim.x + 63) / 64;
    __shared__ float ws[16];

    for (int row = blockIdx.x; row < nrows; row += gridDim.x) {
        const size_t base = (size_t)row * (size_t)D;

        float s = 0.f;
        for (int d = t; d < D; d += blockDim.x) {
            float xv = x[base + d];
            float xm = (mask[base + d] != 0) ? xv : 0.f;
            s += xm * xm;
        }
#pragma unroll
        for (int off = 32; off > 0; off >>= 1) s += __shfl_down(s, off);
        if (lane == 0) ws[wave] = s;
        __syncthreads();
        float total = 0.f;
        for (int i = 0; i < nw; ++i) total += ws[i];
        const float scale = rsqrtf(total / (float)D + EPS_RMS);
        __syncthreads();  // protect ws before next iteration's writes

        for (int d = t; d < D; d += blockDim.x) {
            float xv = x[base + d];
            float xm = (mask[base + d] != 0) ? xv : 0.f;
            out[base + d] = weight[d] * xm * scale;
        }
    }
}

extern "C" void kernel_launch(void* const* d_in, const int* in_sizes, int n_in,
                              void* d_out, int out_size, void* d_ws,
                              size_t ws_size, hipStream_t stream) {
    const float* x = (const float*)d_in[0];
    const int* mask = (const int*)d_in[1];  // fp32 0/1 words; !=0 test
    const float* weight = (const float*)d_in[2];
    float* out = (float*)d_out;

    const int D = in_sizes[2];         // weight length
    const int rows = in_sizes[0] / D;  // B*S

    if (D == 4096) {
        const int blocks = rows < 2048 ? rows : 2048;
        rmsnorm_sparse_fast4096<<<blocks, 256, 0, stream>>>(x, mask, weight,
                                                            out, rows, blocks);
    } else {
        const int blocks = rows < 2048 ? rows : 2048;
        rmsnorm_sparse_generic<<<blocks, 256, 0, stream>>>(x, mask, weight,
                                                           out, D, rows);
    }
}